// Round 14
// baseline (24.276 us; speedup 1.0000x reference)
//
#include <hip/hip_runtime.h>

#define NJ   24
#define BLK  256
#define QMF4 (NJ * 4)           // float4 index of Qm ; +1 = Pm
#define NCPY (NJ * 4 + 2)       // float4s in the LDS constant table
#define INV4PI 0.07957747154594767f
#define FOURPI 12.566370614359172f

// SE(3) element as unit quaternion + translation.
struct DQ { float w, x, y, z, t0, t1, t2; };

// DPP quad_perm broadcast (full-rate VALU, no LDS).
template<int CTRL>
__device__ __forceinline__ float dppmov(float v) {
    return __int_as_float(__builtin_amdgcn_mov_dpp(__float_as_int(v), CTRL, 0xF, 0xF, true));
}
#define DPP_LO 0xA0   // quad_perm [0,0,2,2]: both pair lanes get pair-lane0's value
#define DPP_HI 0xF5   // quad_perm [1,1,3,3]: both pair lanes get pair-lane1's value

// Compose C = A * B  (rotation: A.q (x) B.q ; translation: A.t + rot(A.q, B.t))
__device__ __forceinline__ DQ dq_comp(const DQ A, const DQ B) {
    const float u10 = A.y*B.t2 - A.z*B.t1;
    const float u11 = A.z*B.t0 - A.x*B.t2;
    const float u12 = A.x*B.t1 - A.y*B.t0;
    const float u20 = A.y*u12 - A.z*u11;
    const float u21 = A.z*u10 - A.x*u12;
    const float u22 = A.x*u11 - A.y*u10;
    const float tw  = 2.0f * A.w;
    DQ C;
    C.t0 = fmaf(tw, u10, fmaf(2.0f, u20, A.t0 + B.t0));
    C.t1 = fmaf(tw, u11, fmaf(2.0f, u21, A.t1 + B.t1));
    C.t2 = fmaf(tw, u12, fmaf(2.0f, u22, A.t2 + B.t2));
    C.w = A.w*B.w - A.x*B.x - A.y*B.y - A.z*B.z;
    C.x = A.w*B.x + A.x*B.w + A.y*B.z - A.z*B.y;
    C.y = A.w*B.y - A.x*B.z + A.y*B.w + A.z*B.x;
    C.z = A.w*B.z + A.x*B.y - A.y*B.x + A.z*B.w;
    return C;
}

// ---------------------------------------------------------------------------
// Fused kernel, 2 lanes per batch row (lane h owns joints 12h..12h+11).
// Block prep: threads 0..23 build 4-float4 joint records in LDS, thread 24
// builds exp(M). Each lane runs a 12-joint quaternion chain, the pair
// combines via DPP quad_perm broadcasts (T = T_lo o T_hi computed by both
// lanes, no selection), folds exp(M), and stores two 16B rows of T
// (lane0: rows 0,1; lane1: rows 2,3 -> contiguous 64B per row pair).
// ---------------------------------------------------------------------------
__global__ __launch_bounds__(BLK, 4)
void poe_main(const float* __restrict__ x,
              const float* __restrict__ eta,
              const float* __restrict__ M,
              float* __restrict__ out,
              int nBatch)
{
    __shared__ float4 sC[NCPY];
    float* sF = (float*)sC;

    const int t = threadIdx.x;
    if (t < NJ) {
        const float w0 = eta[t*6+0], w1 = eta[t*6+1], w2 = eta[t*6+2];
        const float v0 = eta[t*6+3], v1 = eta[t*6+4], v2 = eta[t*6+5];
        const float k  = w0*w0 + w1*w1 + w2*w2;
        const bool  sm = (k < 1e-12f);
        const float invsqk = sm ? 0.0f : rsqrtf(k);
        const float sqk    = k * invsqk;
        const float invk   = invsqk * invsqk;
        const float invk15 = invk * invsqk;
        const float c10 = w1*v2 - w2*v1;
        const float c11 = w2*v0 - w0*v2;
        const float c12 = w0*v1 - w1*v0;
        const float c20 = w1*c12 - w2*c11;
        const float c21 = w2*c10 - w0*c12;
        const float c22 = w0*c11 - w1*c10;
        float* r = sF + t * 16;
        r[0]  = w0*invsqk;  r[1]  = w1*invsqk;  r[2]  = w2*invsqk;  r[3]  = sqk;
        r[4]  = v0;         r[5]  = v1;         r[6]  = v2;         r[7]  = sqk * INV4PI;
        r[8]  = c10*invk;   r[9]  = c11*invk;   r[10] = c12*invk;   r[11] = 0.0f;
        r[12] = c20*invk15; r[13] = c21*invk15; r[14] = c22*invk15; r[15] = 0.0f;
    } else if (t == NJ) {
        const float w0 = M[0], w1 = M[1], w2 = M[2];
        const float v0 = M[3], v1 = M[4], v2 = M[5];
        const float t2 = w0*w0 + w1*w1 + w2*w2;
        const bool  sm = (t2 < 1e-12f);
        const float t2s  = sm ? 1.0f : t2;
        const float invt = rsqrtf(t2s);
        const float th   = t2s * invt;
        float s, c;
        __sincosf(th, &s, &c);
        const float invt2 = invt * invt;
        const float B = sm ? 0.5f        : (1.0f - c) * invt2;
        const float C = sm ? (1.0f/6.0f) : (th - s) * invt2 * invt;
        float sh, chh;
        __sincosf(0.5f * th, &sh, &chh);
        const float axs = sm ? 0.5f : sh * invt;   // sin(th/2)/th
        float* r = sF + QMF4 * 4;
        r[0] = sm ? 1.0f : chh;
        r[1] = axs * w0;  r[2] = axs * w1;  r[3] = axs * w2;
        const float a0 = w1*v2 - w2*v1, a1 = w2*v0 - w0*v2, a2 = w0*v1 - w1*v0;
        const float b0 = w1*a2 - w2*a1, b1 = w2*a0 - w0*a2, b2 = w0*a1 - w1*a0;
        r[4] = v0 + B*a0 + C*b0;
        r[5] = v1 + B*a1 + C*b1;
        r[6] = v2 + B*a2 + C*b2;
        r[7] = 0.0f;
    }

    // ---- own 12 joint angles: 3x float4 (16B aligned) ----
    const int gid = blockIdx.x * BLK + t;
    const int row = gid >> 1;
    const int h   = gid & 1;
    const bool active = row < nBatch;

    float4 xz4 = make_float4(0.f,0.f,0.f,0.f);
    float4 xa = xz4, xb = xz4, xc = xz4;
    if (active) {
        const float4* xp = (const float4*)(x + (size_t)row * NJ + h * 12);
        xa = xp[0]; xb = xp[1]; xc = xp[2];
    }

    __syncthreads();

    const int cbase = h * 48;   // float4 index of this lane's first record
    DQ T;

#define JSTEP(JJ, A_, FIRST) do {                                             \
    const float4 A4 = sC[cbase + (JJ)*4 + 0];                                 \
    const float4 B4 = sC[cbase + (JJ)*4 + 1];                                 \
    const float4 C4 = sC[cbase + (JJ)*4 + 2];                                 \
    const float4 D4 = sC[cbase + (JJ)*4 + 3];                                 \
    const float a    = (A_);                                                  \
    const float hrev = a * B4.w;                                              \
    const float sh   = __builtin_amdgcn_sinf(hrev);                           \
    const float ch   = __builtin_amdgcn_cosf(hrev);                           \
    const float s    = 2.0f * sh * ch;          /* sin(phi)   */              \
    const float cB   = 2.0f * sh * sh;          /* 1-cos(phi) */              \
    const float g    = fmaf(FOURPI, hrev, -s);  /* phi-sin(phi) */            \
    DQ e;                                                                     \
    e.w  = ch;                                                                \
    e.x  = sh * A4.x;                                                         \
    e.y  = sh * A4.y;                                                         \
    e.z  = sh * A4.z;                                                         \
    e.t0 = fmaf(a, B4.x, fmaf(cB, C4.x, g * D4.x));                           \
    e.t1 = fmaf(a, B4.y, fmaf(cB, C4.y, g * D4.y));                           \
    e.t2 = fmaf(a, B4.z, fmaf(cB, C4.z, g * D4.z));                           \
    if (FIRST) T = e; else T = dq_comp(T, e);                                 \
} while (0)

    JSTEP( 0, xa.x, true);
    JSTEP( 1, xa.y, false);
    JSTEP( 2, xa.z, false);
    JSTEP( 3, xa.w, false);
    JSTEP( 4, xb.x, false);
    JSTEP( 5, xb.y, false);
    JSTEP( 6, xb.z, false);
    JSTEP( 7, xb.w, false);
    JSTEP( 8, xc.x, false);
    JSTEP( 9, xc.y, false);
    JSTEP(10, xc.z, false);
    JSTEP(11, xc.w, false);
#undef JSTEP

    // ---- pair combine via DPP broadcasts: T = T_pairlo o T_pairhi ----
    {
        DQ A, B;
        A.w  = dppmov<DPP_LO>(T.w);   B.w  = dppmov<DPP_HI>(T.w);
        A.x  = dppmov<DPP_LO>(T.x);   B.x  = dppmov<DPP_HI>(T.x);
        A.y  = dppmov<DPP_LO>(T.y);   B.y  = dppmov<DPP_HI>(T.y);
        A.z  = dppmov<DPP_LO>(T.z);   B.z  = dppmov<DPP_HI>(T.z);
        A.t0 = dppmov<DPP_LO>(T.t0);  B.t0 = dppmov<DPP_HI>(T.t0);
        A.t1 = dppmov<DPP_LO>(T.t1);  B.t1 = dppmov<DPP_HI>(T.t1);
        A.t2 = dppmov<DPP_LO>(T.t2);  B.t2 = dppmov<DPP_HI>(T.t2);
        T = dq_comp(A, B);
    }

    // ---- fold exp(M): T = T * Em ----
    {
        const float4 Qm = sC[QMF4];
        const float4 Pm = sC[QMF4 + 1];
        DQ Em;
        Em.w = Qm.x; Em.x = Qm.y; Em.y = Qm.z; Em.z = Qm.w;
        Em.t0 = Pm.x; Em.t1 = Pm.y; Em.t2 = Pm.z;
        T = dq_comp(T, Em);
    }

    // ---- Q -> R; lane0 stores rows 0,1; lane1 stores rows 2,3 ----
    if (active) {
        const float xx = T.x*T.x, yy = T.y*T.y, zz = T.z*T.z;
        const float xy = T.x*T.y, xzp = T.x*T.z, yz = T.y*T.z;
        const float wx = T.w*T.x, wy = T.w*T.y, wz = T.w*T.z;
        float4* o = (float4*)(out + (size_t)row * 16);
        if (h == 0) {
            o[0] = make_float4(1.0f-2.0f*(yy+zz), 2.0f*(xy-wz),      2.0f*(xzp+wy),     T.t0);
            o[1] = make_float4(2.0f*(xy+wz),      1.0f-2.0f*(xx+zz), 2.0f*(yz-wx),      T.t1);
        } else {
            o[2] = make_float4(2.0f*(xzp-wy),     2.0f*(yz+wx),      1.0f-2.0f*(xx+yy), T.t2);
            o[3] = make_float4(0.0f, 0.0f, 0.0f, 1.0f);
        }
    }
}

extern "C" void kernel_launch(void* const* d_in, const int* in_sizes, int n_in,
                              void* d_out, int out_size, void* d_ws, size_t ws_size,
                              hipStream_t stream)
{
    const float* x   = (const float*)d_in[0];
    const float* eta = (const float*)d_in[1];
    const float* M   = (const float*)d_in[2];
    float* out = (float*)d_out;

    const int nBatch   = in_sizes[0] / NJ;
    const int nThreads = nBatch * 2;
    const int grid     = (nThreads + BLK - 1) / BLK;

    poe_main<<<grid, BLK, 0, stream>>>(x, eta, M, out, nBatch);
}

// Round 15
// 20.525 us; speedup vs baseline: 1.1827x; 1.1827x over previous
//
#include <hip/hip_runtime.h>

#define NJ   24
#define BLK  256
#define QMF4 (NJ * 3)           // float4 index of Qm ; +1 = Pm
#define NCPY (NJ * 3 + 2)       // float4s in the LDS constant table
#define INV4PI 0.07957747154594767f
#define FOURPI 12.566370614359172f

// ---------------- packed (2-row) helpers: row A in .x, row B in .y ---------
__device__ __forceinline__ float2 pk(float a, float b)            { return make_float2(a, b); }
__device__ __forceinline__ float2 pk_mul(float2 a, float2 b)      { return make_float2(a.x*b.x, a.y*b.y); }
__device__ __forceinline__ float2 pk_muls(float2 a, float s)      { return make_float2(a.x*s, a.y*s); }
__device__ __forceinline__ float2 pk_add(float2 a, float2 b)      { return make_float2(a.x+b.x, a.y+b.y); }
__device__ __forceinline__ float2 pk_sub(float2 a, float2 b)      { return make_float2(a.x-b.x, a.y-b.y); }
__device__ __forceinline__ float2 pk_fma(float2 a, float2 b, float2 c) {
    return make_float2(fmaf(a.x,b.x,c.x), fmaf(a.y,b.y,c.y));
}
__device__ __forceinline__ float2 pk_fmas(float2 a, float s, float2 c) {
    return make_float2(fmaf(a.x,s,c.x), fmaf(a.y,s,c.y));
}

// SE(3) element as unit quaternion + translation, two rows packed.
struct DQ2 { float2 w, x, y, z, t0, t1, t2; };
// scalar version for combine/epilogue
struct DQ { float w, x, y, z, t0, t1, t2; };

// Packed compose C = A * B (both rows at once).
__device__ __forceinline__ DQ2 dq2_comp(const DQ2 A, const DQ2 B) {
    const float2 u10 = pk_sub(pk_mul(A.y,B.t2), pk_mul(A.z,B.t1));
    const float2 u11 = pk_sub(pk_mul(A.z,B.t0), pk_mul(A.x,B.t2));
    const float2 u12 = pk_sub(pk_mul(A.x,B.t1), pk_mul(A.y,B.t0));
    const float2 u20 = pk_sub(pk_mul(A.y,u12), pk_mul(A.z,u11));
    const float2 u21 = pk_sub(pk_mul(A.z,u10), pk_mul(A.x,u12));
    const float2 u22 = pk_sub(pk_mul(A.x,u11), pk_mul(A.y,u10));
    const float2 tw  = pk_add(A.w, A.w);
    DQ2 C;
    C.t0 = pk_fma(tw, u10, pk_fma(pk(2.f,2.f), u20, pk_add(A.t0, B.t0)));
    C.t1 = pk_fma(tw, u11, pk_fma(pk(2.f,2.f), u21, pk_add(A.t1, B.t1)));
    C.t2 = pk_fma(tw, u12, pk_fma(pk(2.f,2.f), u22, pk_add(A.t2, B.t2)));
    C.w = pk_sub(pk_sub(pk_sub(pk_mul(A.w,B.w), pk_mul(A.x,B.x)), pk_mul(A.y,B.y)), pk_mul(A.z,B.z));
    C.x = pk_sub(pk_add(pk_add(pk_mul(A.w,B.x), pk_mul(A.x,B.w)), pk_mul(A.y,B.z)), pk_mul(A.z,B.y));
    C.y = pk_add(pk_add(pk_sub(pk_mul(A.w,B.y), pk_mul(A.x,B.z)), pk_mul(A.y,B.w)), pk_mul(A.z,B.x));
    C.z = pk_add(pk_sub(pk_add(pk_mul(A.w,B.z), pk_mul(A.x,B.y)), pk_mul(A.y,B.x)), pk_mul(A.z,B.w));
    return C;
}

// scalar compose (combine/epilogue)
__device__ __forceinline__ DQ dq_comp(const DQ A, const DQ B) {
    const float u10 = A.y*B.t2 - A.z*B.t1;
    const float u11 = A.z*B.t0 - A.x*B.t2;
    const float u12 = A.x*B.t1 - A.y*B.t0;
    const float u20 = A.y*u12 - A.z*u11;
    const float u21 = A.z*u10 - A.x*u12;
    const float u22 = A.x*u11 - A.y*u10;
    const float tw  = 2.0f * A.w;
    DQ C;
    C.t0 = fmaf(tw, u10, fmaf(2.0f, u20, A.t0 + B.t0));
    C.t1 = fmaf(tw, u11, fmaf(2.0f, u21, A.t1 + B.t1));
    C.t2 = fmaf(tw, u12, fmaf(2.0f, u22, A.t2 + B.t2));
    C.w = A.w*B.w - A.x*B.x - A.y*B.y - A.z*B.z;
    C.x = A.w*B.x + A.x*B.w + A.y*B.z - A.z*B.y;
    C.y = A.w*B.y - A.x*B.z + A.y*B.w + A.z*B.x;
    C.z = A.w*B.z + A.x*B.y - A.y*B.x + A.z*B.w;
    return C;
}

__device__ __forceinline__ DQ quad_combine(DQ T, const int q) {
    #pragma unroll
    for (int bit = 1; bit <= 2; bit <<= 1) {
        DQ O;
        O.w  = __shfl_xor(T.w,  bit);  O.x  = __shfl_xor(T.x,  bit);
        O.y  = __shfl_xor(T.y,  bit);  O.z  = __shfl_xor(T.z,  bit);
        O.t0 = __shfl_xor(T.t0, bit);  O.t1 = __shfl_xor(T.t1, bit);
        O.t2 = __shfl_xor(T.t2, bit);
        const bool up = (q & bit) != 0;     // self is the SECOND factor
        DQ A, B;
        A.w  = up ? O.w  : T.w;   B.w  = up ? T.w  : O.w;
        A.x  = up ? O.x  : T.x;   B.x  = up ? T.x  : O.x;
        A.y  = up ? O.y  : T.y;   B.y  = up ? T.y  : O.y;
        A.z  = up ? O.z  : T.z;   B.z  = up ? T.z  : O.z;
        A.t0 = up ? O.t0 : T.t0;  B.t0 = up ? T.t0 : O.t0;
        A.t1 = up ? O.t1 : T.t1;  B.t1 = up ? T.t1 : O.t1;
        A.t2 = up ? O.t2 : T.t2;  B.t2 = up ? T.t2 : O.t2;
        T = dq_comp(A, B);
    }
    return T;
}

__device__ __forceinline__ float4 row_of(const DQ F, const int q) {
    const float xx = F.x*F.x, yy = F.y*F.y, zz = F.z*F.z;
    const float xy = F.x*F.y, xz = F.x*F.z, yz = F.y*F.z;
    const float wx = F.w*F.x, wy = F.w*F.y, wz = F.w*F.z;
    float4 r;
    if      (q == 0) r = make_float4(1.0f-2.0f*(yy+zz), 2.0f*(xy-wz), 2.0f*(xz+wy), F.t0);
    else if (q == 1) r = make_float4(2.0f*(xy+wz), 1.0f-2.0f*(xx+zz), 2.0f*(yz-wx), F.t1);
    else if (q == 2) r = make_float4(2.0f*(xz-wy), 2.0f*(yz+wx), 1.0f-2.0f*(xx+yy), F.t2);
    else             r = make_float4(0.0f, 0.0f, 0.0f, 1.0f);
    return r;
}

// ---------------------------------------------------------------------------
// R13 structure with the 6-joint chain in PACKED float2 math (row A = .x,
// row B = .y) to let the backend emit v_pk_{fma,mul,add}_f32 (dual-FP32).
// 2 rows per thread, 4 lanes per row; 3-float4 joint records in LDS
// (c2' = W x c1' derived once per joint, shared by both rows); quad combine
// + exp(M) fold + Q->R scalar per row; coalesced 16B stores.
// ---------------------------------------------------------------------------
__global__ __launch_bounds__(BLK, 4)
void poe_main(const float* __restrict__ x,
              const float* __restrict__ eta,
              const float* __restrict__ M,
              float* __restrict__ out,
              int nBatch)
{
    __shared__ float4 sC[NCPY];
    float* sF = (float*)sC;

    const int t = threadIdx.x;
    if (t < NJ) {
        const float w0 = eta[t*6+0], w1 = eta[t*6+1], w2 = eta[t*6+2];
        const float v0 = eta[t*6+3], v1 = eta[t*6+4], v2 = eta[t*6+5];
        const float k  = w0*w0 + w1*w1 + w2*w2;
        const bool  sm = (k < 1e-12f);
        const float invsqk = sm ? 0.0f : rsqrtf(k);
        const float sqk    = k * invsqk;
        const float invk   = invsqk * invsqk;
        float* r = sF + t * 12;
        r[0]  = w0*invsqk;        r[1]  = w1*invsqk;
        r[2]  = w2*invsqk;        r[3]  = sqk * INV4PI;
        r[4]  = v0;  r[5]  = v1;  r[6]  = v2;  r[7] = 0.0f;
        r[8]  = (w1*v2 - w2*v1)*invk;
        r[9]  = (w2*v0 - w0*v2)*invk;
        r[10] = (w0*v1 - w1*v0)*invk;
        r[11] = 0.0f;
    } else if (t == NJ) {
        const float w0 = M[0], w1 = M[1], w2 = M[2];
        const float v0 = M[3], v1 = M[4], v2 = M[5];
        const float t2 = w0*w0 + w1*w1 + w2*w2;
        const bool  sm = (t2 < 1e-12f);
        const float t2s  = sm ? 1.0f : t2;
        const float invt = rsqrtf(t2s);
        const float th   = t2s * invt;
        float s, c;
        __sincosf(th, &s, &c);
        const float invt2 = invt * invt;
        const float B = sm ? 0.5f        : (1.0f - c) * invt2;
        const float C = sm ? (1.0f/6.0f) : (th - s) * invt2 * invt;
        float sh, chh;
        __sincosf(0.5f * th, &sh, &chh);
        const float axs = sm ? 0.5f : sh * invt;   // sin(th/2)/th
        float* r = sF + QMF4 * 4;
        r[0] = sm ? 1.0f : chh;
        r[1] = axs * w0;  r[2] = axs * w1;  r[3] = axs * w2;
        const float a0 = w1*v2 - w2*v1, a1 = w2*v0 - w0*v2, a2 = w0*v1 - w1*v0;
        const float b0 = w1*a2 - w2*a1, b1 = w2*a0 - w0*a2, b2 = w0*a1 - w1*a0;
        r[4] = v0 + B*a0 + C*b0;
        r[5] = v1 + B*a1 + C*b1;
        r[6] = v2 + B*a2 + C*b2;
        r[7] = 0.0f;
    }

    // ---- two rows per thread ----
    const int gid  = blockIdx.x * BLK + t;
    const int quad = gid >> 2;
    const int q    = gid & 3;
    const int r0   = quad * 2;
    const int r1   = r0 + 1;
    const bool a0  = r0 < nBatch;
    const bool a1  = r1 < nBatch;

    float2 xa0 = make_float2(0.f,0.f), xb0 = xa0, xc0 = xa0;
    float2 xa1 = xa0, xb1 = xa0, xc1 = xa0;
    if (a0) {
        const float2* xp = (const float2*)(x + (size_t)r0 * NJ + q * 6);
        xa0 = xp[0]; xb0 = xp[1]; xc0 = xp[2];
    }
    if (a1) {
        const float2* xp = (const float2*)(x + (size_t)r1 * NJ + q * 6);
        xa1 = xp[0]; xb1 = xp[1]; xc1 = xp[2];
    }

    __syncthreads();

    const int cbase = q * 18;   // float4 index of this lane's first record
    DQ2 T;

#define JSTEP(JJ, A0_, A1_, FIRST) do {                                       \
    const float4 A4 = sC[cbase + (JJ)*3 + 0];                                 \
    const float4 B4 = sC[cbase + (JJ)*3 + 1];                                 \
    const float4 C4 = sC[cbase + (JJ)*3 + 2];                                 \
    const float c20 = A4.y*C4.z - A4.z*C4.y;   /* c2' = W x c1' */            \
    const float c21 = A4.z*C4.x - A4.x*C4.z;                                  \
    const float c22 = A4.x*C4.y - A4.y*C4.x;                                  \
    const float2 a2   = pk((A0_), (A1_));                                     \
    const float2 hrev = pk_muls(a2, A4.w);                                    \
    const float2 sh   = pk(__builtin_amdgcn_sinf(hrev.x),                     \
                           __builtin_amdgcn_sinf(hrev.y));                    \
    const float2 ch   = pk(__builtin_amdgcn_cosf(hrev.x),                     \
                           __builtin_amdgcn_cosf(hrev.y));                    \
    const float2 s2   = pk_mul(pk_add(sh,sh), ch);       /* sin(phi)   */     \
    const float2 cB   = pk_mul(pk_add(sh,sh), sh);       /* 1-cos(phi) */     \
    const float2 g    = pk_fmas(hrev, FOURPI, pk(-s2.x,-s2.y));               \
    DQ2 e;                                                                    \
    e.w  = ch;                                                                \
    e.x  = pk_muls(sh, A4.x);                                                 \
    e.y  = pk_muls(sh, A4.y);                                                 \
    e.z  = pk_muls(sh, A4.z);                                                 \
    e.t0 = pk_fmas(a2, B4.x, pk_fmas(cB, C4.x, pk_muls(g, c20)));             \
    e.t1 = pk_fmas(a2, B4.y, pk_fmas(cB, C4.y, pk_muls(g, c21)));             \
    e.t2 = pk_fmas(a2, B4.z, pk_fmas(cB, C4.z, pk_muls(g, c22)));             \
    if (FIRST) T = e; else T = dq2_comp(T, e);                                \
} while (0)

    JSTEP(0, xa0.x, xa1.x, true);
    JSTEP(1, xa0.y, xa1.y, false);
    JSTEP(2, xb0.x, xb1.x, false);
    JSTEP(3, xb0.y, xb1.y, false);
    JSTEP(4, xc0.x, xc1.x, false);
    JSTEP(5, xc0.y, xc1.y, false);
#undef JSTEP

    // ---- unpack the two rows, combine across the quad (scalar) ----
    DQ TA, TB;
    TA.w = T.w.x; TA.x = T.x.x; TA.y = T.y.x; TA.z = T.z.x;
    TA.t0 = T.t0.x; TA.t1 = T.t1.x; TA.t2 = T.t2.x;
    TB.w = T.w.y; TB.x = T.x.y; TB.y = T.y.y; TB.z = T.z.y;
    TB.t0 = T.t0.y; TB.t1 = T.t1.y; TB.t2 = T.t2.y;

    TA = quad_combine(TA, q);
    TB = quad_combine(TB, q);

    // ---- fold exp(M) ----
    DQ Em;
    {
        const float4 Qm = sC[QMF4];
        const float4 Pm = sC[QMF4 + 1];
        Em.w = Qm.x; Em.x = Qm.y; Em.y = Qm.z; Em.z = Qm.w;
        Em.t0 = Pm.x; Em.t1 = Pm.y; Em.t2 = Pm.z;
    }
    TA = dq_comp(TA, Em);
    TB = dq_comp(TB, Em);

    // ---- stores: one 16B row per lane per batch-row (coalesced) ----
    if (a0) ((float4*)out)[(size_t)r0 * 4 + q] = row_of(TA, q);
    if (a1) ((float4*)out)[(size_t)r1 * 4 + q] = row_of(TB, q);
}

extern "C" void kernel_launch(void* const* d_in, const int* in_sizes, int n_in,
                              void* d_out, int out_size, void* d_ws, size_t ws_size,
                              hipStream_t stream)
{
    const float* x   = (const float*)d_in[0];
    const float* eta = (const float*)d_in[1];
    const float* M   = (const float*)d_in[2];
    float* out = (float*)d_out;

    const int nBatch   = in_sizes[0] / NJ;
    const int nQuads   = (nBatch + 1) / 2;        // one quad per 2 rows
    const int nThreads = nQuads * 4;
    const int grid     = (nThreads + BLK - 1) / BLK;

    poe_main<<<grid, BLK, 0, stream>>>(x, eta, M, out, nBatch);
}